// Round 1
// baseline (1662.416 us; speedup 1.0000x reference)
//
#include <hip/hip_runtime.h>

// Problem constants (match reference)
#define B_  32
#define S_  2048
#define H_  4096
#define R_  64

typedef __attribute__((ext_vector_type(8))) short  bf16x8;
typedef __attribute__((ext_vector_type(4))) float  f32x4;

// round-half-up fp32 -> bf16 pack of two floats into one u32 (lo in low 16)
__device__ __forceinline__ unsigned pkbf(float a, float b) {
    unsigned ua = __builtin_bit_cast(unsigned, a) + 0x8000u;
    unsigned ub = __builtin_bit_cast(unsigned, b) + 0x8000u;
    return (ua >> 16) | (ub & 0xFFFF0000u);
}

__device__ __forceinline__ bf16x8 cvt8(f32x4 lo, f32x4 hi) {
    union { unsigned u[4]; bf16x8 v; } r;
    r.u[0] = pkbf(lo[0], lo[1]);
    r.u[1] = pkbf(lo[2], lo[3]);
    r.u[2] = pkbf(hi[0], hi[1]);
    r.u[3] = pkbf(hi[2], hi[3]);
    return r.v;
}

// 256-thread block = 4 independent waves. Block owns 64 rows of one request;
// each wave computes a 16(row) x 64(col) tile with mfma_f32_16x16x32_bf16.
// Grid = 1024 blocks -> 4096 waves = 16 waves/CU = 4 waves/SIMD (was 1/SIMD).
// x is ping-pong register-prefetched (issue one full k-64 iteration ahead ->
// counted vmcnt, not a drain); w comes from XCD-local L2 with a single-buffer
// reload per half-step (residual latency covered by co-resident waves).
__global__ __launch_bounds__(256, 4) void multilora_mfma(
        const float* __restrict__ x,      // [B,S,H]
        const int*   __restrict__ ids,    // [B]
        const float* __restrict__ w,      // [NA,R,H]
        float*       __restrict__ out) {  // [B,S,R]
    const int nblk = B_ * (S_ / 64);      // 1024
    const int raw  = blockIdx.x;
    // Bijective chunked XCD swizzle (1024 % 8 == 0): XCD c gets logical blocks
    // [c*128, (c+1)*128) = 4 consecutive requests = <=4 adapters (<=4MB w) in
    // its private L2.
    const int blk  = (raw & 7) * (nblk >> 3) + (raw >> 3);

    const int b   = blk >> 5;             // 32 row-blocks per request (S/64)
    const int s0  = (blk & 31) << 6;
    const int a   = ids[b];

    const int wid  = threadIdx.x >> 6;    // wave id 0..3: rows s0+wid*16..+16
    const int lane = threadIdx.x & 63;
    const int l15  = lane & 15;
    const int quad = lane >> 4;           // k sub-offset = quad*8

    const float* ap = x + ((size_t)b * S_ + s0 + wid * 16 + l15) * H_ + quad * 8;
    const float* wp0;
    const float* wp1;
    const float* wp2;
    const float* wp3;
    {
        const float* wbase = w + ((size_t)a * R_ + l15) * H_ + quad * 8;
        wp0 = wbase;
        wp1 = wbase + (size_t)16 * H_;
        wp2 = wbase + (size_t)32 * H_;
        wp3 = wbase + (size_t)48 * H_;
    }

    f32x4 acc[4];
#pragma unroll
    for (int i = 0; i < 4; ++i) acc[i] = (f32x4){0.f, 0.f, 0.f, 0.f};

    // register staging: x ping-pong (2 half-steps deep), w single buffer
    f32x4 xA0, xA1, xB0, xB1;
    f32x4 ws[4][2];

    xA0 = *(const f32x4*)(ap);
    xA1 = *(const f32x4*)(ap + 4);
    xB0 = *(const f32x4*)(ap + 32);
    xB1 = *(const f32x4*)(ap + 36);
    ws[0][0] = *(const f32x4*)(wp0);  ws[0][1] = *(const f32x4*)(wp0 + 4);
    ws[1][0] = *(const f32x4*)(wp1);  ws[1][1] = *(const f32x4*)(wp1 + 4);
    ws[2][0] = *(const f32x4*)(wp2);  ws[2][1] = *(const f32x4*)(wp2 + 4);
    ws[3][0] = *(const f32x4*)(wp3);  ws[3][1] = *(const f32x4*)(wp3 + 4);

    for (int k = 0; k < H_; k += 64) {
        // ---- half 1: consume x[k..k+32) (xA) and w[k..k+32) (ws) ----
        bf16x8 bfr[4];
#pragma unroll
        for (int i = 0; i < 4; ++i) bfr[i] = cvt8(ws[i][0], ws[i][1]);
        if (k + 32 < H_) {   // reload w for half 2 (L2-served)
            ws[0][0] = *(const f32x4*)(wp0 + 32);  ws[0][1] = *(const f32x4*)(wp0 + 36);
            ws[1][0] = *(const f32x4*)(wp1 + 32);  ws[1][1] = *(const f32x4*)(wp1 + 36);
            ws[2][0] = *(const f32x4*)(wp2 + 32);  ws[2][1] = *(const f32x4*)(wp2 + 36);
            ws[3][0] = *(const f32x4*)(wp3 + 32);  ws[3][1] = *(const f32x4*)(wp3 + 36);
        }
        bf16x8 af = cvt8(xA0, xA1);
        if (k + 64 < H_) {   // x prefetch 2 half-steps ahead (HBM latency)
            xA0 = *(const f32x4*)(ap + 64);
            xA1 = *(const f32x4*)(ap + 68);
        }
#pragma unroll
        for (int i = 0; i < 4; ++i)
            acc[i] = __builtin_amdgcn_mfma_f32_16x16x32_bf16(af, bfr[i], acc[i], 0, 0, 0);

        // ---- half 2: consume x[k+32..k+64) (xB) and w[k+32..k+64) ----
#pragma unroll
        for (int i = 0; i < 4; ++i) bfr[i] = cvt8(ws[i][0], ws[i][1]);
        if (k + 64 < H_) {   // reload w for next iteration's half 1
            ws[0][0] = *(const f32x4*)(wp0 + 64);  ws[0][1] = *(const f32x4*)(wp0 + 68);
            ws[1][0] = *(const f32x4*)(wp1 + 64);  ws[1][1] = *(const f32x4*)(wp1 + 68);
            ws[2][0] = *(const f32x4*)(wp2 + 64);  ws[2][1] = *(const f32x4*)(wp2 + 68);
            ws[3][0] = *(const f32x4*)(wp3 + 64);  ws[3][1] = *(const f32x4*)(wp3 + 68);
        }
        af = cvt8(xB0, xB1);
        if (k + 96 < H_) {
            xB0 = *(const f32x4*)(ap + 96);
            xB1 = *(const f32x4*)(ap + 100);
        }
#pragma unroll
        for (int i = 0; i < 4; ++i)
            acc[i] = __builtin_amdgcn_mfma_f32_16x16x32_bf16(af, bfr[i], acc[i], 0, 0, 0);

        ap += 64;
        wp0 += 64; wp1 += 64; wp2 += 64; wp3 += 64;
    }

    // Epilogue: C/D layout col = lane&15 (+ni*16), row = quad*4 + reg (m89-verified)
    float* ob = out + ((size_t)b * S_ + s0 + wid * 16) * R_ + l15;
#pragma unroll
    for (int i = 0; i < 4; ++i) {
        float* p = ob + (size_t)(quad * 4 + i) * R_;
#pragma unroll
        for (int ni = 0; ni < 4; ++ni)
            p[ni * 16] = acc[ni][i];
    }
}

extern "C" void kernel_launch(void* const* d_in, const int* in_sizes, int n_in,
                              void* d_out, int out_size, void* d_ws, size_t ws_size,
                              hipStream_t stream) {
    const float* x   = (const float*)d_in[0];
    const int*   ids = (const int*)d_in[1];
    const float* w   = (const float*)d_in[2];
    float*       out = (float*)d_out;

    const int grid = B_ * (S_ / 64);   // 1024 blocks x 256 threads = 4096 waves
    multilora_mfma<<<grid, 256, 0, stream>>>(x, ids, w, out);
}

// Round 2
// 1338.421 us; speedup vs baseline: 1.2421x; 1.2421x over previous
//
#include <hip/hip_runtime.h>

// Problem constants (match reference)
#define B_  32
#define S_  2048
#define H_  4096
#define R_  64
#define NT  64          // H/64 k-tiles

typedef __attribute__((ext_vector_type(8))) short  bf16x8;
typedef __attribute__((ext_vector_type(4))) float  f32x4;

// round-half-up fp32 -> bf16 pack of two floats into one u32 (lo in low 16)
__device__ __forceinline__ unsigned pkbf(float a, float b) {
    unsigned ua = __builtin_bit_cast(unsigned, a) + 0x8000u;
    unsigned ub = __builtin_bit_cast(unsigned, b) + 0x8000u;
    return (ua >> 16) | (ub & 0xFFFF0000u);
}

__device__ __forceinline__ bf16x8 cvt8(f32x4 lo, f32x4 hi) {
    union { unsigned u[4]; bf16x8 v; } r;
    r.u[0] = pkbf(lo[0], lo[1]);
    r.u[1] = pkbf(lo[2], lo[3]);
    r.u[2] = pkbf(hi[0], hi[1]);
    r.u[3] = pkbf(hi[2], hi[3]);
    return r.v;
}

// 512-thread block = 8 waves, block tile = 128 rows x 64 cols of one request.
// w staged ONCE per block per k-tile (64 k) into LDS as bf16 in MFMA-fragment
// order [ks][ni][lane] -> lane-linear ds_read_b128, conflict-free, no per-use
// conversion. x goes global->reg directly (natural fragment layout, no reuse),
// ping-pong prefetched 2 k-tiles ahead. Barriers are raw s_barrier +
// lgkmcnt(0) so the x prefetch queue (vmcnt) survives across k-tiles.
__global__ __launch_bounds__(512, 4) void multilora_mfma(
        const float* __restrict__ x,      // [B,S,H]
        const int*   __restrict__ ids,    // [B]
        const float* __restrict__ w,      // [NA,R,H]
        float*       __restrict__ out) {  // [B,S,R]
    __shared__ bf16x8 lw[2][512];         // 2 x 8 KB: [buf][(ks*4+ni)*64+lane]

    const int raw = blockIdx.x;           // 512 blocks
    // bijective XCD-chunked swizzle (512 % 8 == 0): XCD c owns blocks
    // [c*64,(c+1)*64) = 4 consecutive requests -> <=4 adapters in its L2.
    const int blk = (raw & 7) * 64 + (raw >> 3);
    const int b   = blk >> 4;             // 16 row-blocks per request (S/128)
    const int s0  = (blk & 15) << 7;
    const int a   = ids[b];

    const int tid  = threadIdx.x;
    const int wid  = tid >> 6;            // wave 0..7 -> rows s0+wid*16..+16
    const int lane = tid & 63;
    const int l15  = lane & 15;
    const int quad = lane >> 4;

    // x: this lane's A-fragment row, k sub-offset quad*8
    const float* ap = x + ((size_t)b * S_ + s0 + wid * 16 + l15) * H_ + quad * 8;
    // w staging: thread stages row=lane, k-chunk=wid (8 floats) of each k-tile
    const float* wp = w + ((size_t)a * R_ + lane) * H_ + wid * 8;
    // its fragment slot: ks=wid>>2, q=wid&3, ni=lane>>4, r=lane&15
    const int slot_w = ((wid >> 2) * 4 + (lane >> 4)) * 64 + (wid & 3) * 16 + l15;

    f32x4 acc[4];
#pragma unroll
    for (int i = 0; i < 4; ++i) acc[i] = (f32x4){0.f, 0.f, 0.f, 0.f};

    // ---- prologue: x tiles 0,1 -> regs; w tile 0 -> LDS buf0; issue w tile 1
    f32x4 xA[4], xB[4], wg0, wg1;
    xA[0] = *(const f32x4*)(ap);
    xA[1] = *(const f32x4*)(ap + 4);
    xA[2] = *(const f32x4*)(ap + 32);
    xA[3] = *(const f32x4*)(ap + 36);
    xB[0] = *(const f32x4*)(ap + 64);
    xB[1] = *(const f32x4*)(ap + 68);
    xB[2] = *(const f32x4*)(ap + 96);
    xB[3] = *(const f32x4*)(ap + 100);
    wg0 = *(const f32x4*)(wp);
    wg1 = *(const f32x4*)(wp + 4);
    lw[0][slot_w] = cvt8(wg0, wg1);
    wg0 = *(const f32x4*)(wp + 64);       // prefetch w tile 1
    wg1 = *(const f32x4*)(wp + 68);
    asm volatile("s_waitcnt lgkmcnt(0)" ::: "memory");
    __builtin_amdgcn_s_barrier();
    __builtin_amdgcn_sched_barrier(0);

    // ---- main loop: 31 branch-free double k-tiles (t0=2tt even, t1 odd)
    for (int tt = 0; tt < 31; ++tt) {
        // even tile t0=2tt: read lw[0], consume xA; stage tile t0+1 -> lw[1]
        {
            bf16x8 a0 = cvt8(xA[0], xA[1]);
            bf16x8 a1 = cvt8(xA[2], xA[3]);
            const float* p = ap + (size_t)(2 * tt + 2) * 64;   // x tile t0+2
            xA[0] = *(const f32x4*)(p);
            xA[1] = *(const f32x4*)(p + 4);
            xA[2] = *(const f32x4*)(p + 32);
            xA[3] = *(const f32x4*)(p + 36);
#pragma unroll
            for (int ni = 0; ni < 4; ++ni)
                acc[ni] = __builtin_amdgcn_mfma_f32_16x16x32_bf16(
                    a0, lw[0][ni * 64 + lane], acc[ni], 0, 0, 0);
#pragma unroll
            for (int ni = 0; ni < 4; ++ni)
                acc[ni] = __builtin_amdgcn_mfma_f32_16x16x32_bf16(
                    a1, lw[0][256 + ni * 64 + lane], acc[ni], 0, 0, 0);
            lw[1][slot_w] = cvt8(wg0, wg1);                    // w tile t0+1
            const float* q = wp + (size_t)(2 * tt + 2) * 64;   // w tile t0+2
            wg0 = *(const f32x4*)(q);
            wg1 = *(const f32x4*)(q + 4);
            asm volatile("s_waitcnt lgkmcnt(0)" ::: "memory");
            __builtin_amdgcn_s_barrier();
            __builtin_amdgcn_sched_barrier(0);
        }
        // odd tile t1=2tt+1: read lw[1], consume xB; stage tile t1+1 -> lw[0]
        {
            bf16x8 a0 = cvt8(xB[0], xB[1]);
            bf16x8 a1 = cvt8(xB[2], xB[3]);
            const float* p = ap + (size_t)(2 * tt + 3) * 64;   // x tile t1+2
            xB[0] = *(const f32x4*)(p);
            xB[1] = *(const f32x4*)(p + 4);
            xB[2] = *(const f32x4*)(p + 32);
            xB[3] = *(const f32x4*)(p + 36);
#pragma unroll
            for (int ni = 0; ni < 4; ++ni)
                acc[ni] = __builtin_amdgcn_mfma_f32_16x16x32_bf16(
                    a0, lw[1][ni * 64 + lane], acc[ni], 0, 0, 0);
#pragma unroll
            for (int ni = 0; ni < 4; ++ni)
                acc[ni] = __builtin_amdgcn_mfma_f32_16x16x32_bf16(
                    a1, lw[1][256 + ni * 64 + lane], acc[ni], 0, 0, 0);
            lw[0][slot_w] = cvt8(wg0, wg1);                    // w tile t1+1
            const float* q = wp + (size_t)(2 * tt + 3) * 64;   // w tile t1+2
            wg0 = *(const f32x4*)(q);
            wg1 = *(const f32x4*)(q + 4);
            asm volatile("s_waitcnt lgkmcnt(0)" ::: "memory");
            __builtin_amdgcn_s_barrier();
            __builtin_amdgcn_sched_barrier(0);
        }
    }

    // ---- tail: tiles 62 (even, stages tile 63) and 63 (odd, no staging)
    {
        bf16x8 a0 = cvt8(xA[0], xA[1]);
        bf16x8 a1 = cvt8(xA[2], xA[3]);
#pragma unroll
        for (int ni = 0; ni < 4; ++ni)
            acc[ni] = __builtin_amdgcn_mfma_f32_16x16x32_bf16(
                a0, lw[0][ni * 64 + lane], acc[ni], 0, 0, 0);
#pragma unroll
        for (int ni = 0; ni < 4; ++ni)
            acc[ni] = __builtin_amdgcn_mfma_f32_16x16x32_bf16(
                a1, lw[0][256 + ni * 64 + lane], acc[ni], 0, 0, 0);
        lw[1][slot_w] = cvt8(wg0, wg1);                        // w tile 63
        asm volatile("s_waitcnt lgkmcnt(0)" ::: "memory");
        __builtin_amdgcn_s_barrier();
        __builtin_amdgcn_sched_barrier(0);
    }
    {
        bf16x8 a0 = cvt8(xB[0], xB[1]);
        bf16x8 a1 = cvt8(xB[2], xB[3]);
#pragma unroll
        for (int ni = 0; ni < 4; ++ni)
            acc[ni] = __builtin_amdgcn_mfma_f32_16x16x32_bf16(
                a0, lw[1][ni * 64 + lane], acc[ni], 0, 0, 0);
#pragma unroll
        for (int ni = 0; ni < 4; ++ni)
            acc[ni] = __builtin_amdgcn_mfma_f32_16x16x32_bf16(
                a1, lw[1][256 + ni * 64 + lane], acc[ni], 0, 0, 0);
    }

    // Epilogue: C/D layout col = lane&15 (+ni*16), row = quad*4 + reg
    float* ob = out + ((size_t)b * S_ + s0 + wid * 16) * R_ + l15;
#pragma unroll
    for (int i = 0; i < 4; ++i) {
        float* prow = ob + (size_t)(quad * 4 + i) * R_;
#pragma unroll
        for (int ni = 0; ni < 4; ++ni)
            prow[ni * 16] = acc[ni][i];
    }
}

extern "C" void kernel_launch(void* const* d_in, const int* in_sizes, int n_in,
                              void* d_out, int out_size, void* d_ws, size_t ws_size,
                              hipStream_t stream) {
    const float* x   = (const float*)d_in[0];
    const int*   ids = (const int*)d_in[1];
    const float* w   = (const float*)d_in[2];
    float*       out = (float*)d_out;

    const int grid = B_ * (S_ / 128);   // 512 blocks x 512 threads
    multilora_mfma<<<grid, 512, 0, stream>>>(x, ids, w, out);
}